// Round 8
// baseline (875.153 us; speedup 1.0000x reference)
//
#include <hip/hip_runtime.h>
#include <math.h>

#define PI_F 3.14159265358979323846f
#define IMG 65536  // 256*256
#define RW 4       // rows per wave (4 => v[4][4]=32 VGPR state; total <=64 ->
                   // 8 waves/SIMD vs 4 at VGPR=80. Round-8 occupancy lever.)

__device__ __forceinline__ float2 cmul(float2 a, float2 b) {
  return make_float2(a.x * b.x - a.y * b.y, a.x * b.y + a.y * b.x);
}
__device__ __forceinline__ float2 shflx(float2 v, int m) {
  return make_float2(__shfl_xor(v.x, m, 64), __shfl_xor(v.y, m, 64));
}

// DPP-based lane exchange for masks expressible in DPP16:
//   xor1 = quad_perm [1,0,3,2] = 0xB1
//   xor2 = quad_perm [2,3,0,1] = 0x4E
//   xor8 = row_ror:8          = 0x128
// These run on the VALU pipe; stages 4/16/32 stay on the DS pipe (shflx).
// PIPE BALANCE (round-7 lesson): DS ops co-issue with VALU for free; moving
// ALL stages to VALU (permlane swaps) regressed 500->520 us. Keep the mix.
// Verified win (round 3): k_u2_p1 157 -> 127 us, VALUBusy 25 -> 35%.
template <int CTRL>
__device__ __forceinline__ float2 dppx(float2 v) {
  float2 r;
  r.x = __int_as_float(__builtin_amdgcn_update_dpp(
      0, __float_as_int(v.x), CTRL, 0xf, 0xf, true));
  r.y = __int_as_float(__builtin_amdgcn_update_dpp(
      0, __float_as_int(v.y), CTRL, 0xf, 0xf, true));
  return r;
}
__device__ __forceinline__ float2 partner(float2 v, int s) {
  switch (s) {
    case 1: return dppx<0xB1>(v);
    case 2: return dppx<0x4E>(v);
    case 8: return dppx<0x128>(v);
    default: return shflx(v, s);  // 4, 16, 32 on DS pipe
  }
}

// Precomputed per-lane twiddles. w[t] is the stage twiddle for s = 32>>t
// (identity on lo lanes). q1..q3 are the radix-4 column twiddles.
struct Tw { float2 w[5]; float2 q1, q2, q3; };

// sign = -1 forward, +1 inverse
__device__ __forceinline__ void tw_make(int lane, float sign, Tw& T) {
  #pragma unroll
  for (int t = 0; t < 5; ++t) {
    int s = 32 >> t;
    if (lane & s) {
      float ang = sign * PI_F * (float)(lane & (s - 1)) / (float)s;
      float sn, cs; __sincosf(ang, &sn, &cs);
      T.w[t] = make_float2(cs, sn);
    } else {
      T.w[t] = make_float2(1.f, 0.f);
    }
  }
  float ang = sign * 2.f * PI_F * (float)lane * (1.f / 256.f);
  float sn, cs; __sincosf(ang, &sn, &cs);
  T.q1 = make_float2(cs, sn);
  T.q2 = cmul(T.q1, T.q1);
  T.q3 = cmul(T.q2, T.q1);
}

// ---- batched 256-pt FFT: RW rows per wave, 4 regs/row, 64 lanes ----
// Layout: lane l, reg j <-> position/slot l + 64*j. Forward emits a fixed
// permuted slot order; inverse consumes the same order (products are
// slot-wise, so the permutation never needs materializing).

template <int R>
__device__ __forceinline__ void fwd256_b(float2 (&v)[R][4], int lane, const Tw& T) {
  #pragma unroll
  for (int r = 0; r < R; ++r) {
    float2 a = v[r][0], b = v[r][1], c = v[r][2], d = v[r][3];
    float2 e0 = make_float2(a.x + c.x, a.y + c.y);
    float2 o0 = make_float2(a.x - c.x, a.y - c.y);
    float2 e1 = make_float2(b.x + d.x, b.y + d.y);
    float2 o1 = make_float2(b.x - d.x, b.y - d.y);
    v[r][0] = make_float2(e0.x + e1.x, e0.y + e1.y);
    v[r][2] = cmul(make_float2(e0.x - e1.x, e0.y - e1.y), T.q2);
    v[r][1] = cmul(make_float2(o0.x + o1.y, o0.y - o1.x), T.q1);  // o0 - i*o1
    v[r][3] = cmul(make_float2(o0.x - o1.y, o0.y + o1.x), T.q3);  // o0 + i*o1
  }
  #pragma unroll
  for (int t = 0; t < 5; ++t) {
    int s = 32 >> t;
    float sg = (lane & s) ? -1.f : 1.f;
    float2 w = T.w[t];
    #pragma unroll
    for (int r = 0; r < R; ++r)
      #pragma unroll
      for (int j = 0; j < 4; ++j) {
        float2 p = partner(v[r][j], s);
        float2 u = make_float2(p.x + sg * v[r][j].x, p.y + sg * v[r][j].y);
        v[r][j] = cmul(u, w);
      }
  }
  { // s = 1, twiddle = 1
    float sg = (lane & 1) ? -1.f : 1.f;
    #pragma unroll
    for (int r = 0; r < R; ++r)
      #pragma unroll
      for (int j = 0; j < 4; ++j) {
        float2 p = partner(v[r][j], 1);
        v[r][j] = make_float2(p.x + sg * v[r][j].x, p.y + sg * v[r][j].y);
      }
  }
}

template <int R>
__device__ __forceinline__ void inv256_b(float2 (&v)[R][4], int lane, const Tw& T) {
  { // s = 1 first, twiddle = 1
    float sg = (lane & 1) ? -1.f : 1.f;
    #pragma unroll
    for (int r = 0; r < R; ++r)
      #pragma unroll
      for (int j = 0; j < 4; ++j) {
        float2 p = partner(v[r][j], 1);
        v[r][j] = make_float2(p.x + sg * v[r][j].x, p.y + sg * v[r][j].y);
      }
  }
  #pragma unroll
  for (int t = 0; t < 5; ++t) {
    int s = 2 << t;                 // 2,4,8,16,32
    float sg = (lane & s) ? -1.f : 1.f;
    float2 w = T.w[4 - t];          // w[] indexed by s = 32>>idx
    #pragma unroll
    for (int r = 0; r < R; ++r)
      #pragma unroll
      for (int j = 0; j < 4; ++j) {
        float2 z = cmul(v[r][j], w);
        float2 p = partner(z, s);
        v[r][j] = make_float2(p.x + sg * z.x, p.y + sg * z.y);
      }
  }
  #pragma unroll
  for (int r = 0; r < R; ++r) {
    float2 a = v[r][0], b = cmul(v[r][1], T.q1);
    float2 c = cmul(v[r][2], T.q2), d = cmul(v[r][3], T.q3);
    float2 e0 = make_float2(a.x + c.x, a.y + c.y);
    float2 o0 = make_float2(a.x - c.x, a.y - c.y);
    float2 e1 = make_float2(b.x + d.x, b.y + d.y);
    float2 o1 = make_float2(b.x - d.x, b.y - d.y);
    v[r][0] = make_float2(e0.x + e1.x, e0.y + e1.y);
    v[r][2] = make_float2(e0.x - e1.x, e0.y - e1.y);
    v[r][1] = make_float2(o0.x - o1.y, o0.y + o1.x);  // o0 + i*o1
    v[r][3] = make_float2(o0.x + o1.y, o0.y - o1.x);  // o0 - i*o1
  }
}

// ---- memory helpers (no LDS anywhere) ----

template <int R>
__device__ __forceinline__ void loadRows(const float2* bp, int r0, float2 (&v)[R][4], int l) {
  #pragma unroll
  for (int ri = 0; ri < R; ++ri) {
    const float2* rp = bp + (size_t)(r0 + ri) * 256 + l;
    #pragma unroll
    for (int j = 0; j < 4; ++j) v[ri][j] = rp[64 * j];
  }
}
template <int R>
__device__ __forceinline__ void storeRows(float2* bp, int r0, float2 (&v)[R][4], int l) {
  #pragma unroll
  for (int ri = 0; ri < R; ++ri) {
    float2* rp = bp + (size_t)(r0 + ri) * 256 + l;
    #pragma unroll
    for (int j = 0; j < 4; ++j) rp[64 * j] = v[ri][j];
  }
}
// transposed store: column c = l+64j gets rows r0..r0+R-1 contiguous
template <int R>
__device__ __forceinline__ void storeT(float2* OT, int r0, float2 (&v)[R][4], int l) {
  #pragma unroll
  for (int j = 0; j < 4; ++j) {
    int c = l + 64 * j;
    float4* dst = (float4*)(OT + (size_t)c * 256 + r0);
    #pragma unroll
    for (int k = 0; k < R / 2; ++k)
      dst[k] = make_float4(v[2 * k][j].x, v[2 * k][j].y,
                           v[2 * k + 1][j].x, v[2 * k + 1][j].y);
  }
}

// ---------------- filter construction ----------------

__global__ __launch_bounds__(256) void k_sums(const float* th, const float* xi,
                                              const float* sg, const float* sl,
                                              float* sums) {
  int f = blockIdx.x, t = threadIdx.x;
  float c, s;
  sincosf(th[f], &s, &c);
  float X = xi[f], S = sg[f], SL = sl[f];
  float a0x = SL * c / S, a0y = SL * s / S, a1x = -s / S, a1y = c / S;
  float gs = 0.f, wr = 0.f, wi = 0.f;
  for (int p = t; p < IMG; p += 256) {
    float gm = (float)((p >> 8) - 128);
    float gn = (float)((p & 255) - 128);
    float r0 = a0x * gm + a0y * gn, r1 = a1x * gm + a1y * gn;
    float g = __expf(-0.5f * (r0 * r0 + r1 * r1));
    float sp, cp;
    sincosf(X * (c * gm + s * gn), &sp, &cp);
    gs += g; wr += cp * g; wi += sp * g;
  }
  __shared__ float red[3][256];
  red[0][t] = gs; red[1][t] = wr; red[2][t] = wi;
  __syncthreads();
  for (int o = 128; o > 0; o >>= 1) {
    if (t < o) {
      red[0][t] += red[0][t + o];
      red[1][t] += red[1][t + o];
      red[2][t] += red[2][t + o];
    }
    __syncthreads();
  }
  if (t == 0) {
    sums[f * 3 + 0] = red[0][0];
    sums[f * 3 + 1] = red[1][0];
    sums[f * 3 + 2] = red[2][0];
  }
}

// merged preamble pass1: y<9 -> psi spatial eval (f=y, f=8 is phi);
// y>=9 -> x image (y-9). Both: fwd FFT along n + transposed store to tmp[y].
// grid (16, 17)
__global__ __launch_bounds__(256) void k_pre1(const float* __restrict__ x,
                                              const float* th, const float* xi,
                                              const float* sg_, const float* sl,
                                              const float* sums, float2* outT) {
  int w = threadIdx.x >> 6, l = threadIdx.x & 63;
  int y = blockIdx.y;
  int r0 = blockIdx.x * (RW * 4) + w * RW;
  float2 v[RW][4];
  if (y >= 9) {  // x path
    int img = y - 9;
    #pragma unroll
    for (int ri = 0; ri < RW; ++ri) {
      const float* rp = x + (size_t)img * IMG + (size_t)(r0 + ri) * 256 + l;
      #pragma unroll
      for (int j = 0; j < 4; ++j) v[ri][j] = make_float2(rp[64 * j], 0.f);
    }
  } else {       // psi/phi path
    int f = y;
    bool isPhi = (f == 8);
    float T_ = 0.f, X = 0.f, S = 3.2f, SL = 1.f, Kr = 0.f, Ki = 0.f;
    if (!isPhi) {
      T_ = th[f]; X = xi[f]; S = sg_[f]; SL = sl[f];
      float gs = sums[f * 3];
      Kr = sums[f * 3 + 1] / gs;
      Ki = sums[f * 3 + 2] / gs;
    }
    float c, s;
    sincosf(T_, &s, &c);
    float a0x = SL * c / S, a0y = SL * s / S, a1x = -s / S, a1y = c / S;
    float inorm = SL / (2.f * PI_F * S * S);
    #pragma unroll
    for (int ri = 0; ri < RW; ++ri) {
      int m = r0 + ri;
      float gm = (m < 128) ? (float)m : (float)(m - 256);
      #pragma unroll
      for (int j = 0; j < 4; ++j) {
        int n = l + 64 * j;
        float gn = (n < 128) ? (float)n : (float)(n - 256);
        float rr0 = a0x * gm + a0y * gn, rr1 = a1x * gm + a1y * gn;
        float g = __expf(-0.5f * (rr0 * rr0 + rr1 * rr1));
        float sp, cp;
        sincosf(X * (c * gm + s * gn), &sp, &cp);
        float re = isPhi ? g : (cp - Kr) * g;
        float im = isPhi ? 0.f : (sp - Ki) * g;
        v[ri][j] = make_float2(re * inorm, im * inorm);
      }
    }
  }
  Tw T; tw_make(l, -1.f, T);
  fwd256_b<RW>(v, l, T);
  storeT<RW>(outT + (size_t)y * IMG, r0, v, l);
}

// straight forward FFT (in==out OK). grid (16, imgs)
__global__ __launch_bounds__(256, 8) void k_fwdS(const float2* in, float2* out) {
  int w = threadIdx.x >> 6, l = threadIdx.x & 63;
  int img = blockIdx.y, r0 = blockIdx.x * (RW * 4) + w * RW;
  float2 v[RW][4];
  loadRows<RW>(in + (size_t)img * IMG, r0, v, l);
  Tw T; tw_make(l, -1.f, T);
  fwd256_b<RW>(v, l, T);
  storeRows<RW>(out + (size_t)img * IMG, r0, v, l);
}

// U1 pass1 (incl. phi as f=8): Xh*psi -> inv over m -> transposed -> T1 (parked
// in out's U2 slots). grid (16, 72); y = i*9 + f
__global__ __launch_bounds__(256, 8) void k_u1_p1(const float2* __restrict__ XhT,
                                                  const float2* __restrict__ psiT,
                                                  float* out) {
  int w = threadIdx.x >> 6, l = threadIdx.x & 63;
  int y = blockIdx.y, i = y / 9, f = y - i * 9;
  int r0 = blockIdx.x * (RW * 4) + w * RW;
  const float2* A = XhT + (size_t)i * IMG;
  const float2* P = psiT + (size_t)f * IMG;
  float2 v[RW][4];
  #pragma unroll
  for (int ri = 0; ri < RW; ++ri) {
    const float2* ap = A + (size_t)(r0 + ri) * 256 + l;
    const float2* pp = P + (size_t)(r0 + ri) * 256 + l;
    #pragma unroll
    for (int j = 0; j < 4; ++j) v[ri][j] = cmul(ap[64 * j], pp[64 * j]);
  }
  Tw T; tw_make(l, 1.f, T);
  inv256_b<RW>(v, l, T);
  storeT<RW>((float2*)out + ((size_t)(i * 73 + 9 + 2 * f)) * 32768, r0, v, l);
}

// U1 pass2: T1 -> inv over n. f<8: modulus -> U1 out, fwd over n -> T2 (transposed).
// f==8: real part -> S0 out. grid (16, 72)
__global__ __launch_bounds__(256, 8) void k_u1_p2(float* out, float2* T2) {
  int w = threadIdx.x >> 6, l = threadIdx.x & 63;
  int y = blockIdx.y, i = y / 9, f = y - i * 9;
  int r0 = blockIdx.x * (RW * 4) + w * RW;
  float2 v[RW][4];
  loadRows<RW>((const float2*)out + ((size_t)(i * 73 + 9 + 2 * f)) * 32768, r0, v, l);
  Tw Ti; tw_make(l, 1.f, Ti);
  inv256_b<RW>(v, l, Ti);
  if (f == 8) {
    float* op = out + (size_t)(i * 73) * IMG;
    #pragma unroll
    for (int ri = 0; ri < RW; ++ri)
      #pragma unroll
      for (int j = 0; j < 4; ++j)
        op[(size_t)(r0 + ri) * 256 + l + 64 * j] = v[ri][j].x * (1.f / 65536.f);
    return;
  }
  float* uo = out + (size_t)(i * 73 + 1 + f) * IMG;
  #pragma unroll
  for (int ri = 0; ri < RW; ++ri)
    #pragma unroll
    for (int j = 0; j < 4; ++j) {
      float2 z = v[ri][j];
      float mod = sqrtf(z.x * z.x + z.y * z.y) * (1.f / 65536.f);
      uo[(size_t)(r0 + ri) * 256 + l + 64 * j] = mod;
      v[ri][j] = make_float2(mod, 0.f);
    }
  Tw Tf; tw_make(l, -1.f, Tf);
  fwd256_b<RW>(v, l, Tf);
  storeT<RW>(T2 + (size_t)(i * 8 + f) * IMG, r0, v, l);
}

// U2 pass1: U1hT[ii*8+f1]*psiT[f2] -> inv over m -> transposed -> T3.
// grid (16, CQ*8); y -> q = q0 + y/8 (q = f1*8+ii), f2 = y&7
__global__ __launch_bounds__(256, 8) void k_u2_p1(const float2* __restrict__ U1hT,
                                                  const float2* __restrict__ psiT,
                                                  float2* __restrict__ T3, int q0) {
  int w = threadIdx.x >> 6, l = threadIdx.x & 63;
  int y = blockIdx.y, q = q0 + (y >> 3), f2 = y & 7;
  int f1 = q >> 3, ii = q & 7;
  int r0 = blockIdx.x * (RW * 4) + w * RW;
  const float2* A = U1hT + (size_t)(ii * 8 + f1) * IMG;
  const float2* P = psiT + (size_t)f2 * IMG;
  float2 v[RW][4];
  #pragma unroll
  for (int ri = 0; ri < RW; ++ri) {
    const float2* ap = A + (size_t)(r0 + ri) * 256 + l;
    const float2* pp = P + (size_t)(r0 + ri) * 256 + l;
    #pragma unroll
    for (int j = 0; j < 4; ++j) v[ri][j] = cmul(ap[64 * j], pp[64 * j]);
  }
  Tw T; tw_make(l, 1.f, T);
  inv256_b<RW>(v, l, T);
  storeT<RW>(T3 + (size_t)y * IMG, r0, v, l);
}

// U2 pass2: T3 -> inv over n -> modulus -> out. grid (16, CQ*8)
__global__ __launch_bounds__(256, 8) void k_u2_p2(const float2* __restrict__ T3,
                                                  float* __restrict__ out, int q0) {
  int w = threadIdx.x >> 6, l = threadIdx.x & 63;
  int y = blockIdx.y, q = q0 + (y >> 3), f2 = y & 7;
  int f1 = q >> 3, ii = q & 7;
  int r0 = blockIdx.x * (RW * 4) + w * RW;
  float2 v[RW][4];
  loadRows<RW>(T3 + (size_t)y * IMG, r0, v, l);
  Tw T; tw_make(l, 1.f, T);
  inv256_b<RW>(v, l, T);
  float* op = out + (size_t)(ii * 73 + 9 + f1 * 8 + f2) * IMG;
  #pragma unroll
  for (int ri = 0; ri < RW; ++ri)
    #pragma unroll
    for (int j = 0; j < 4; ++j) {
      float2 z = v[ri][j];
      op[(size_t)(r0 + ri) * 256 + l + 64 * j] =
          sqrtf(z.x * z.x + z.y * z.y) * (1.f / 65536.f);
    }
}

extern "C" void kernel_launch(void* const* d_in, const int* in_sizes, int n_in,
                              void* d_out, int out_size, void* d_ws, size_t ws_size,
                              hipStream_t stream) {
  const float* x  = (const float*)d_in[0];
  const float* th = (const float*)d_in[1];
  const float* xi = (const float*)d_in[2];
  const float* sg = (const float*)d_in[3];
  const float* sl = (const float*)d_in[4];
  float* out = (float*)d_out;

  // ws: [sums 1KB][psiT 9][XhT 8][T2 64][T3 CQ*8] images of 64K float2
  float* sums  = (float*)d_ws;
  float2* psiT = (float2*)((char*)d_ws + 1024);
  float2* XhT  = psiT + (size_t)9 * IMG;   // contiguous after psiT (merged fwdS)
  float2* T2   = XhT + (size_t)8 * IMG;    // U1h (64 imgs); early temp region
  float2* T3   = T2 + (size_t)64 * IMG;
  float2* tmp17 = T2;                      // pre1 temp (17 imgs, dead early)

  size_t base = 1024 + (size_t)(9 + 8 + 64) * IMG * sizeof(float2);
  // CQ: U2 chunking. Timing-neutral between 16 and 64 (round 5 A/B) —
  // the U2 kernels are latency-bound, not HBM-bound. Keep 16 (smaller ws).
  int CQ = 16;
  while (CQ > 1 && base + (size_t)CQ * 8 * IMG * sizeof(float2) > ws_size) CQ >>= 1;

  int GX = 256 / (RW * 4);  // blocks along rows (16 rows per 256-thread block)
  dim3 B(256);
  k_sums <<<dim3(8),      B, 0, stream>>>(th, xi, sg, sl, sums);
  k_pre1 <<<dim3(GX, 17), B, 0, stream>>>(x, th, xi, sg, sl, sums, tmp17);
  k_fwdS <<<dim3(GX, 17), B, 0, stream>>>(tmp17, psiT);    // -> psiT[0..8], XhT[0..7]
  k_u1_p1<<<dim3(GX, 72), B, 0, stream>>>(XhT, psiT, out); // S0+U1 pass1 -> T1
  k_u1_p2<<<dim3(GX, 72), B, 0, stream>>>(out, T2);        // S0/U1 out, fwd -> T2
  k_fwdS <<<dim3(GX, 64), B, 0, stream>>>(T2, T2);         // U1h: fft m in-place
  for (int q0 = 0; q0 < 64; q0 += CQ) {
    k_u2_p1<<<dim3(GX, CQ * 8), B, 0, stream>>>(T2, psiT, T3, q0);
    k_u2_p2<<<dim3(GX, CQ * 8), B, 0, stream>>>(T3, out, q0);
  }
}

// Round 9
// 483.760 us; speedup vs baseline: 1.8091x; 1.8091x over previous
//
#include <hip/hip_runtime.h>
#include <math.h>

#define PI_F 3.14159265358979323846f
#define IMG 65536  // 256*256
#define RW 4       // rows per wave; block of 4 waves covers 16 rows.
// Round-8 lesson: RW=4 with DIRECT transposed scatter writes 32 B/lane =
// half cache lines -> RMW write-allocate (FETCH 7->117 MB). Fix below:
// LDS-staged block transpose restores full-line stores (128 B/thread)
// while keeping the 32-VGPR state that doubles occupancy (27->58%).

__device__ __forceinline__ float2 cmul(float2 a, float2 b) {
  return make_float2(a.x * b.x - a.y * b.y, a.x * b.y + a.y * b.x);
}
__device__ __forceinline__ float2 shflx(float2 v, int m) {
  return make_float2(__shfl_xor(v.x, m, 64), __shfl_xor(v.y, m, 64));
}

// DPP-based lane exchange for masks expressible in DPP16:
//   xor1 = quad_perm [1,0,3,2] = 0xB1
//   xor2 = quad_perm [2,3,0,1] = 0x4E
//   xor8 = row_ror:8          = 0x128
// These run on the VALU pipe; stages 4/16/32 stay on the DS pipe (shflx).
// PIPE BALANCE (round-7 lesson): moving ALL stages to VALU regressed.
// Verified win (round 3): k_u2_p1 157 -> 127 us.
template <int CTRL>
__device__ __forceinline__ float2 dppx(float2 v) {
  float2 r;
  r.x = __int_as_float(__builtin_amdgcn_update_dpp(
      0, __float_as_int(v.x), CTRL, 0xf, 0xf, true));
  r.y = __int_as_float(__builtin_amdgcn_update_dpp(
      0, __float_as_int(v.y), CTRL, 0xf, 0xf, true));
  return r;
}
__device__ __forceinline__ float2 partner(float2 v, int s) {
  switch (s) {
    case 1: return dppx<0xB1>(v);
    case 2: return dppx<0x4E>(v);
    case 8: return dppx<0x128>(v);
    default: return shflx(v, s);  // 4, 16, 32 on DS pipe
  }
}

// Precomputed per-lane twiddles. w[t] is the stage twiddle for s = 32>>t
// (identity on lo lanes). q1..q3 are the radix-4 column twiddles.
struct Tw { float2 w[5]; float2 q1, q2, q3; };

// sign = -1 forward, +1 inverse
__device__ __forceinline__ void tw_make(int lane, float sign, Tw& T) {
  #pragma unroll
  for (int t = 0; t < 5; ++t) {
    int s = 32 >> t;
    if (lane & s) {
      float ang = sign * PI_F * (float)(lane & (s - 1)) / (float)s;
      float sn, cs; __sincosf(ang, &sn, &cs);
      T.w[t] = make_float2(cs, sn);
    } else {
      T.w[t] = make_float2(1.f, 0.f);
    }
  }
  float ang = sign * 2.f * PI_F * (float)lane * (1.f / 256.f);
  float sn, cs; __sincosf(ang, &sn, &cs);
  T.q1 = make_float2(cs, sn);
  T.q2 = cmul(T.q1, T.q1);
  T.q3 = cmul(T.q2, T.q1);
}

// ---- batched 256-pt FFT: RW rows per wave, 4 regs/row, 64 lanes ----
// Layout: lane l, reg j <-> position/slot l + 64*j. Forward emits a fixed
// permuted slot order; inverse consumes the same order (products are
// slot-wise, so the permutation never needs materializing).

__device__ __forceinline__ void fwd256_b(float2 (&v)[RW][4], int lane, const Tw& T) {
  #pragma unroll
  for (int r = 0; r < RW; ++r) {
    float2 a = v[r][0], b = v[r][1], c = v[r][2], d = v[r][3];
    float2 e0 = make_float2(a.x + c.x, a.y + c.y);
    float2 o0 = make_float2(a.x - c.x, a.y - c.y);
    float2 e1 = make_float2(b.x + d.x, b.y + d.y);
    float2 o1 = make_float2(b.x - d.x, b.y - d.y);
    v[r][0] = make_float2(e0.x + e1.x, e0.y + e1.y);
    v[r][2] = cmul(make_float2(e0.x - e1.x, e0.y - e1.y), T.q2);
    v[r][1] = cmul(make_float2(o0.x + o1.y, o0.y - o1.x), T.q1);  // o0 - i*o1
    v[r][3] = cmul(make_float2(o0.x - o1.y, o0.y + o1.x), T.q3);  // o0 + i*o1
  }
  #pragma unroll
  for (int t = 0; t < 5; ++t) {
    int s = 32 >> t;
    float sg = (lane & s) ? -1.f : 1.f;
    float2 w = T.w[t];
    #pragma unroll
    for (int r = 0; r < RW; ++r)
      #pragma unroll
      for (int j = 0; j < 4; ++j) {
        float2 p = partner(v[r][j], s);
        float2 u = make_float2(p.x + sg * v[r][j].x, p.y + sg * v[r][j].y);
        v[r][j] = cmul(u, w);
      }
  }
  { // s = 1, twiddle = 1
    float sg = (lane & 1) ? -1.f : 1.f;
    #pragma unroll
    for (int r = 0; r < RW; ++r)
      #pragma unroll
      for (int j = 0; j < 4; ++j) {
        float2 p = partner(v[r][j], 1);
        v[r][j] = make_float2(p.x + sg * v[r][j].x, p.y + sg * v[r][j].y);
      }
  }
}

__device__ __forceinline__ void inv256_b(float2 (&v)[RW][4], int lane, const Tw& T) {
  { // s = 1 first, twiddle = 1
    float sg = (lane & 1) ? -1.f : 1.f;
    #pragma unroll
    for (int r = 0; r < RW; ++r)
      #pragma unroll
      for (int j = 0; j < 4; ++j) {
        float2 p = partner(v[r][j], 1);
        v[r][j] = make_float2(p.x + sg * v[r][j].x, p.y + sg * v[r][j].y);
      }
  }
  #pragma unroll
  for (int t = 0; t < 5; ++t) {
    int s = 2 << t;                 // 2,4,8,16,32
    float sg = (lane & s) ? -1.f : 1.f;
    float2 w = T.w[4 - t];          // w[] indexed by s = 32>>idx
    #pragma unroll
    for (int r = 0; r < RW; ++r)
      #pragma unroll
      for (int j = 0; j < 4; ++j) {
        float2 z = cmul(v[r][j], w);
        float2 p = partner(z, s);
        v[r][j] = make_float2(p.x + sg * z.x, p.y + sg * z.y);
      }
  }
  #pragma unroll
  for (int r = 0; r < RW; ++r) {
    float2 a = v[r][0], b = cmul(v[r][1], T.q1);
    float2 c = cmul(v[r][2], T.q2), d = cmul(v[r][3], T.q3);
    float2 e0 = make_float2(a.x + c.x, a.y + c.y);
    float2 o0 = make_float2(a.x - c.x, a.y - c.y);
    float2 e1 = make_float2(b.x + d.x, b.y + d.y);
    float2 o1 = make_float2(b.x - d.x, b.y - d.y);
    v[r][0] = make_float2(e0.x + e1.x, e0.y + e1.y);
    v[r][2] = make_float2(e0.x - e1.x, e0.y - e1.y);
    v[r][1] = make_float2(o0.x - o1.y, o0.y + o1.x);  // o0 + i*o1
    v[r][3] = make_float2(o0.x + o1.y, o0.y - o1.x);  // o0 - i*o1
  }
}

// ---- memory helpers ----

__device__ __forceinline__ void loadRows(const float2* bp, int r0, float2 (&v)[RW][4], int l) {
  #pragma unroll
  for (int ri = 0; ri < RW; ++ri) {
    const float2* rp = bp + (size_t)(r0 + ri) * 256 + l;
    #pragma unroll
    for (int j = 0; j < 4; ++j) v[ri][j] = rp[64 * j];
  }
}
__device__ __forceinline__ void storeRows(float2* bp, int r0, float2 (&v)[RW][4], int l) {
  #pragma unroll
  for (int ri = 0; ri < RW; ++ri) {
    float2* rp = bp + (size_t)(r0 + ri) * 256 + l;
    #pragma unroll
    for (int j = 0; j < 4; ++j) rp[64 * j] = v[ri][j];
  }
}

// LDS-staged transposed store. Block = 4 waves = rows R0..R0+15.
// Stage rows into a 16x256 tile (one barrier), then thread t writes
// column t: 16 float2 = 128 B contiguous (2 full cache lines).
// Bank check (32 banks x 4B): write tile[row][l+64j] -> bank (2l)%32,
// 2 lanes/bank (free, m136); read tile[k][c], k uniform -> bank (2c)%32,
// 2 lanes/bank (free). Must be the LAST op of the kernel (no 2nd barrier).
__device__ __forceinline__ void storeT_lds(float2* OT, int R0,
                                           float2 (&v)[RW][4], int w, int l) {
  __shared__ float2 tile[16][256];  // 32 KB -> 5 blocks/CU LDS cap
  #pragma unroll
  for (int ri = 0; ri < RW; ++ri)
    #pragma unroll
    for (int j = 0; j < 4; ++j)
      tile[w * RW + ri][l + 64 * j] = v[ri][j];
  __syncthreads();
  int c = w * 64 + l;  // == threadIdx.x
  float4* dst = (float4*)(OT + (size_t)c * 256 + R0);
  #pragma unroll
  for (int k = 0; k < 8; ++k) {
    float2 a = tile[2 * k][c], b = tile[2 * k + 1][c];
    dst[k] = make_float4(a.x, a.y, b.x, b.y);
  }
}

// ---------------- filter construction ----------------

__global__ __launch_bounds__(256) void k_sums(const float* th, const float* xi,
                                              const float* sg, const float* sl,
                                              float* sums) {
  int f = blockIdx.x, t = threadIdx.x;
  float c, s;
  sincosf(th[f], &s, &c);
  float X = xi[f], S = sg[f], SL = sl[f];
  float a0x = SL * c / S, a0y = SL * s / S, a1x = -s / S, a1y = c / S;
  float gs = 0.f, wr = 0.f, wi = 0.f;
  for (int p = t; p < IMG; p += 256) {
    float gm = (float)((p >> 8) - 128);
    float gn = (float)((p & 255) - 128);
    float r0 = a0x * gm + a0y * gn, r1 = a1x * gm + a1y * gn;
    float g = __expf(-0.5f * (r0 * r0 + r1 * r1));
    float sp, cp;
    sincosf(X * (c * gm + s * gn), &sp, &cp);
    gs += g; wr += cp * g; wi += sp * g;
  }
  __shared__ float red[3][256];
  red[0][t] = gs; red[1][t] = wr; red[2][t] = wi;
  __syncthreads();
  for (int o = 128; o > 0; o >>= 1) {
    if (t < o) {
      red[0][t] += red[0][t + o];
      red[1][t] += red[1][t + o];
      red[2][t] += red[2][t + o];
    }
    __syncthreads();
  }
  if (t == 0) {
    sums[f * 3 + 0] = red[0][0];
    sums[f * 3 + 1] = red[1][0];
    sums[f * 3 + 2] = red[2][0];
  }
}

// merged preamble pass1: y<9 -> psi spatial eval (f=y, f=8 is phi);
// y>=9 -> x image (y-9). Both: fwd FFT along n + transposed store to tmp[y].
// grid (16, 17)
__global__ __launch_bounds__(256) void k_pre1(const float* __restrict__ x,
                                              const float* th, const float* xi,
                                              const float* sg_, const float* sl,
                                              const float* sums, float2* outT) {
  int w = threadIdx.x >> 6, l = threadIdx.x & 63;
  int y = blockIdx.y;
  int R0 = blockIdx.x * 16;
  int r0 = R0 + w * RW;
  float2 v[RW][4];
  if (y >= 9) {  // x path
    int img = y - 9;
    #pragma unroll
    for (int ri = 0; ri < RW; ++ri) {
      const float* rp = x + (size_t)img * IMG + (size_t)(r0 + ri) * 256 + l;
      #pragma unroll
      for (int j = 0; j < 4; ++j) v[ri][j] = make_float2(rp[64 * j], 0.f);
    }
  } else {       // psi/phi path
    int f = y;
    bool isPhi = (f == 8);
    float T_ = 0.f, X = 0.f, S = 3.2f, SL = 1.f, Kr = 0.f, Ki = 0.f;
    if (!isPhi) {
      T_ = th[f]; X = xi[f]; S = sg_[f]; SL = sl[f];
      float gs = sums[f * 3];
      Kr = sums[f * 3 + 1] / gs;
      Ki = sums[f * 3 + 2] / gs;
    }
    float c, s;
    sincosf(T_, &s, &c);
    float a0x = SL * c / S, a0y = SL * s / S, a1x = -s / S, a1y = c / S;
    float inorm = SL / (2.f * PI_F * S * S);
    #pragma unroll
    for (int ri = 0; ri < RW; ++ri) {
      int m = r0 + ri;
      float gm = (m < 128) ? (float)m : (float)(m - 256);
      #pragma unroll
      for (int j = 0; j < 4; ++j) {
        int n = l + 64 * j;
        float gn = (n < 128) ? (float)n : (float)(n - 256);
        float rr0 = a0x * gm + a0y * gn, rr1 = a1x * gm + a1y * gn;
        float g = __expf(-0.5f * (rr0 * rr0 + rr1 * rr1));
        float sp, cp;
        sincosf(X * (c * gm + s * gn), &sp, &cp);
        float re = isPhi ? g : (cp - Kr) * g;
        float im = isPhi ? 0.f : (sp - Ki) * g;
        v[ri][j] = make_float2(re * inorm, im * inorm);
      }
    }
  }
  Tw T; tw_make(l, -1.f, T);
  fwd256_b(v, l, T);
  storeT_lds(outT + (size_t)y * IMG, R0, v, w, l);
}

// straight forward FFT (in==out OK). grid (16, imgs)
__global__ __launch_bounds__(256) void k_fwdS(const float2* in, float2* out) {
  int w = threadIdx.x >> 6, l = threadIdx.x & 63;
  int img = blockIdx.y, r0 = blockIdx.x * 16 + w * RW;
  float2 v[RW][4];
  loadRows(in + (size_t)img * IMG, r0, v, l);
  Tw T; tw_make(l, -1.f, T);
  fwd256_b(v, l, T);
  storeRows(out + (size_t)img * IMG, r0, v, l);
}

// U1 pass1 (incl. phi as f=8): Xh*psi -> inv over m -> transposed -> T1 (parked
// in out's U2 slots). grid (16, 72); y = i*9 + f
__global__ __launch_bounds__(256) void k_u1_p1(const float2* __restrict__ XhT,
                                               const float2* __restrict__ psiT,
                                               float* out) {
  int w = threadIdx.x >> 6, l = threadIdx.x & 63;
  int y = blockIdx.y, i = y / 9, f = y - i * 9;
  int R0 = blockIdx.x * 16;
  int r0 = R0 + w * RW;
  const float2* A = XhT + (size_t)i * IMG;
  const float2* P = psiT + (size_t)f * IMG;
  float2 v[RW][4];
  #pragma unroll
  for (int ri = 0; ri < RW; ++ri) {
    const float2* ap = A + (size_t)(r0 + ri) * 256 + l;
    const float2* pp = P + (size_t)(r0 + ri) * 256 + l;
    #pragma unroll
    for (int j = 0; j < 4; ++j) v[ri][j] = cmul(ap[64 * j], pp[64 * j]);
  }
  Tw T; tw_make(l, 1.f, T);
  inv256_b(v, l, T);
  storeT_lds((float2*)out + ((size_t)(i * 73 + 9 + 2 * f)) * 32768, R0, v, w, l);
}

// U1 pass2: T1 -> inv over n. f<8: modulus -> U1 out, fwd over n -> T2 (transposed).
// f==8: real part -> S0 out. grid (16, 72)
__global__ __launch_bounds__(256) void k_u1_p2(float* out, float2* T2) {
  int w = threadIdx.x >> 6, l = threadIdx.x & 63;
  int y = blockIdx.y, i = y / 9, f = y - i * 9;
  int R0 = blockIdx.x * 16;
  int r0 = R0 + w * RW;
  float2 v[RW][4];
  loadRows((const float2*)out + ((size_t)(i * 73 + 9 + 2 * f)) * 32768, r0, v, l);
  Tw Ti; tw_make(l, 1.f, Ti);
  inv256_b(v, l, Ti);
  if (f == 8) {
    float* op = out + (size_t)(i * 73) * IMG;
    #pragma unroll
    for (int ri = 0; ri < RW; ++ri)
      #pragma unroll
      for (int j = 0; j < 4; ++j)
        op[(size_t)(r0 + ri) * 256 + l + 64 * j] = v[ri][j].x * (1.f / 65536.f);
    return;
  }
  float* uo = out + (size_t)(i * 73 + 1 + f) * IMG;
  #pragma unroll
  for (int ri = 0; ri < RW; ++ri)
    #pragma unroll
    for (int j = 0; j < 4; ++j) {
      float2 z = v[ri][j];
      float mod = sqrtf(z.x * z.x + z.y * z.y) * (1.f / 65536.f);
      uo[(size_t)(r0 + ri) * 256 + l + 64 * j] = mod;
      v[ri][j] = make_float2(mod, 0.f);
    }
  Tw Tf; tw_make(l, -1.f, Tf);
  fwd256_b(v, l, Tf);
  storeT_lds(T2 + (size_t)(i * 8 + f) * IMG, R0, v, w, l);
}

// U2 pass1: U1hT[ii*8+f1]*psiT[f2] -> inv over m -> transposed -> T3.
// grid (16, CQ*8); y -> q = q0 + y/8 (q = f1*8+ii), f2 = y&7
__global__ __launch_bounds__(256) void k_u2_p1(const float2* __restrict__ U1hT,
                                               const float2* __restrict__ psiT,
                                               float2* __restrict__ T3, int q0) {
  int w = threadIdx.x >> 6, l = threadIdx.x & 63;
  int y = blockIdx.y, q = q0 + (y >> 3), f2 = y & 7;
  int f1 = q >> 3, ii = q & 7;
  int R0 = blockIdx.x * 16;
  int r0 = R0 + w * RW;
  const float2* A = U1hT + (size_t)(ii * 8 + f1) * IMG;
  const float2* P = psiT + (size_t)f2 * IMG;
  float2 v[RW][4];
  #pragma unroll
  for (int ri = 0; ri < RW; ++ri) {
    const float2* ap = A + (size_t)(r0 + ri) * 256 + l;
    const float2* pp = P + (size_t)(r0 + ri) * 256 + l;
    #pragma unroll
    for (int j = 0; j < 4; ++j) v[ri][j] = cmul(ap[64 * j], pp[64 * j]);
  }
  Tw T; tw_make(l, 1.f, T);
  inv256_b(v, l, T);
  storeT_lds(T3 + (size_t)y * IMG, R0, v, w, l);
}

// U2 pass2: T3 -> inv over n -> modulus -> out. grid (16, CQ*8)
__global__ __launch_bounds__(256) void k_u2_p2(const float2* __restrict__ T3,
                                               float* __restrict__ out, int q0) {
  int w = threadIdx.x >> 6, l = threadIdx.x & 63;
  int y = blockIdx.y, q = q0 + (y >> 3), f2 = y & 7;
  int f1 = q >> 3, ii = q & 7;
  int r0 = blockIdx.x * 16 + w * RW;
  float2 v[RW][4];
  loadRows(T3 + (size_t)y * IMG, r0, v, l);
  Tw T; tw_make(l, 1.f, T);
  inv256_b(v, l, T);
  float* op = out + (size_t)(ii * 73 + 9 + f1 * 8 + f2) * IMG;
  #pragma unroll
  for (int ri = 0; ri < RW; ++ri)
    #pragma unroll
    for (int j = 0; j < 4; ++j) {
      float2 z = v[ri][j];
      op[(size_t)(r0 + ri) * 256 + l + 64 * j] =
          sqrtf(z.x * z.x + z.y * z.y) * (1.f / 65536.f);
    }
}

extern "C" void kernel_launch(void* const* d_in, const int* in_sizes, int n_in,
                              void* d_out, int out_size, void* d_ws, size_t ws_size,
                              hipStream_t stream) {
  const float* x  = (const float*)d_in[0];
  const float* th = (const float*)d_in[1];
  const float* xi = (const float*)d_in[2];
  const float* sg = (const float*)d_in[3];
  const float* sl = (const float*)d_in[4];
  float* out = (float*)d_out;

  // ws: [sums 1KB][psiT 9][XhT 8][T2 64][T3 CQ*8] images of 64K float2
  float* sums  = (float*)d_ws;
  float2* psiT = (float2*)((char*)d_ws + 1024);
  float2* XhT  = psiT + (size_t)9 * IMG;   // contiguous after psiT (merged fwdS)
  float2* T2   = XhT + (size_t)8 * IMG;    // U1h (64 imgs); early temp region
  float2* T3   = T2 + (size_t)64 * IMG;
  float2* tmp17 = T2;                      // pre1 temp (17 imgs, dead early)

  size_t base = 1024 + (size_t)(9 + 8 + 64) * IMG * sizeof(float2);
  // CQ: U2 chunking. Timing-neutral between 16 and 64 (round 5 A/B).
  int CQ = 16;
  while (CQ > 1 && base + (size_t)CQ * 8 * IMG * sizeof(float2) > ws_size) CQ >>= 1;

  const int GX = 16;  // 16 rows per block (4 waves x RW=4)
  dim3 B(256);
  k_sums <<<dim3(8),      B, 0, stream>>>(th, xi, sg, sl, sums);
  k_pre1 <<<dim3(GX, 17), B, 0, stream>>>(x, th, xi, sg, sl, sums, tmp17);
  k_fwdS <<<dim3(GX, 17), B, 0, stream>>>(tmp17, psiT);    // -> psiT[0..8], XhT[0..7]
  k_u1_p1<<<dim3(GX, 72), B, 0, stream>>>(XhT, psiT, out); // S0+U1 pass1 -> T1
  k_u1_p2<<<dim3(GX, 72), B, 0, stream>>>(out, T2);        // S0/U1 out, fwd -> T2
  k_fwdS <<<dim3(GX, 64), B, 0, stream>>>(T2, T2);         // U1h: fft m in-place
  for (int q0 = 0; q0 < 64; q0 += CQ) {
    k_u2_p1<<<dim3(GX, CQ * 8), B, 0, stream>>>(T2, psiT, T3, q0);
    k_u2_p2<<<dim3(GX, CQ * 8), B, 0, stream>>>(T3, out, q0);
  }
}